// Round 15
// baseline (323.161 us; speedup 1.0000x reference)
//
#include <hip/hip_runtime.h>
#include <hip/hip_bf16.h>

// MSDNet on MI355X. Only scale 2's chain matters (scales 0/1 dead), and
// final_logits == logits at depth 3.
// conv_mfma v11 = v10/r12 (70.4us/conv) + T4 counted-vmcnt phases:
//   Barrier A (start): issue batch(P+1) -> vmcnt(4) (batch P landed, P+1 in
//   flight ACROSS the barrier) -> s_barrier.
//   Barrier B (end): lgkmcnt(0)-only s_barrier (buffer-reuse guard, no drain).
//   + s_setprio(1) around MFMA clusters (T5).
// Geometry frozen: 256 thr / 4 waves of 64px x 64co, quad-buffered W via
// block-cooperative gload16 from pre-swizzled image, q-streamed A, 3 blk/CU.

typedef unsigned int uint;
typedef unsigned short u16;
typedef __bf16 bf16x8 __attribute__((ext_vector_type(8)));
typedef short short8 __attribute__((ext_vector_type(8)));
typedef unsigned short ushort8 __attribute__((ext_vector_type(8)));
typedef float f32x4 __attribute__((ext_vector_type(4)));

#define NB   16
#define CCH  128
#define NCLS 100
#define HW   12544      // 112*112
#define NTILE 98        // 14 h-tiles x 7 w-tiles per image

__device__ __forceinline__ u16 f2bf(float f) {
    uint u = __float_as_uint(f);
    return (u16)((u + 0x7fffu + ((u >> 16) & 1u)) >> 16);
}

__device__ __forceinline__ void gload16(const u16* g, u16* l) {
    __builtin_amdgcn_global_load_lds(
        (const __attribute__((address_space(1))) uint*)g,
        (__attribute__((address_space(3))) uint*)l, 16, 0, 0);
}

// ---------------- weight convert: block_w[d][2][co][ci][kh][kw] f32 ->
// per-step LDS images wbs[d][s][4096]: slot (co,gpos,e) holds
// W[tap(s)][co][ q(s)*32 + (gpos ^ ((co>>1)&3))*8 + e ]   (s = q*9 + tap)
__global__ __launch_bounds__(256) void convert_w(
    const float* __restrict__ bw, u16* __restrict__ wbs)
{
    int idx = blockIdx.x * 256 + threadIdx.x;        // 4 * 36 * 4096
    if (idx >= 4 * 147456) return;
    int d = idx / 147456, r = idx % 147456;
    int s = r >> 12;                 // 0..35
    int p = r & 4095;
    int co = p >> 5, gpos = (p >> 3) & 3, e = p & 7;
    int q = s / 9, t = s % 9;
    int cin = q * 32 + ((gpos ^ ((co >> 1) & 3)) << 3) + e;
    float v = bw[(((size_t)(d * 3 + 2) * 128 + co) * 128 + cin) * 9 + t];
    wbs[idx] = f2bf(v);
}

// ---------------- init conv: cin=3, fp32 VALU, NCHW fp32 in -> NHWC bf16 out ----------------
__global__ __launch_bounds__(256) void conv_init(
    const float* __restrict__ in,    // [16][3][112][112]
    const float* __restrict__ wgt,   // [128][3][3][3]
    const float* __restrict__ bias,  // [128]
    u16* __restrict__ outp)          // [16][12544][128] bf16
{
    const int tile = blockIdx.x;          // 0..48 (16x16 tiles)
    const int cg   = blockIdx.y;          // 0..3  (32 couts)
    const int n    = blockIdx.z;
    const int h0 = (tile / 7) * 16, w0 = (tile % 7) * 16;
    const int tid = threadIdx.x;
    const int sid = tid & 63, wv = tid >> 6;
    const int tx = sid & 7, ty = sid >> 3;

    __shared__ float s_in[3][18][18];
    __shared__ float s_w[3][9][32];

    float acc[2][2][8];
    #pragma unroll
    for (int a = 0; a < 2; a++)
        #pragma unroll
        for (int b = 0; b < 2; b++)
            #pragma unroll
            for (int c = 0; c < 8; c++) acc[a][b][c] = 0.f;

    const float* in_n = in + (size_t)n * 3 * HW;
    const int cbase = cg * 32;

    for (int e = tid; e < 3 * 324; e += 256) {
        int ck = e / 324, p = e % 324;
        int y = p / 18, x = p % 18;
        int gh = h0 + y - 1, gw = w0 + x - 1;
        float v = 0.f;
        if ((unsigned)gh < 112u && (unsigned)gw < 112u)
            v = in_n[(size_t)ck * HW + gh * 112 + gw];
        s_in[ck][y][x] = v;
    }
    for (int e = tid; e < 3 * 9 * 32; e += 256) {
        int co = e / 27, r = e % 27;
        int ck = r / 9, kidx = r % 9;
        s_w[ck][kidx][co] = wgt[((size_t)(cbase + co) * 3 + ck) * 9 + kidx];
    }
    __syncthreads();

    #pragma unroll
    for (int ck = 0; ck < 3; ck++) {
        float rowv[4][4];
        #pragma unroll
        for (int r = 0; r < 4; r++) {
            float2 a  = *(const float2*)&s_in[ck][ty * 2 + r][tx * 2];
            float2 b2 = *(const float2*)&s_in[ck][ty * 2 + r][tx * 2 + 2];
            rowv[r][0] = a.x; rowv[r][1] = a.y;
            rowv[r][2] = b2.x; rowv[r][3] = b2.y;
        }
        #pragma unroll
        for (int kh = 0; kh < 3; kh++)
            #pragma unroll
            for (int kw = 0; kw < 3; kw++) {
                float i00 = rowv[kh][kw],     i01 = rowv[kh][kw + 1];
                float i10 = rowv[kh + 1][kw], i11 = rowv[kh + 1][kw + 1];
                const float* wp = &s_w[ck][kh * 3 + kw][wv * 8];
                #pragma unroll
                for (int co = 0; co < 8; co++) {
                    float wval = wp[co];
                    acc[0][0][co] += i00 * wval;
                    acc[0][1][co] += i01 * wval;
                    acc[1][0][co] += i10 * wval;
                    acc[1][1][co] += i11 * wval;
                }
            }
    }

    float bv[8];
    #pragma unroll
    for (int co = 0; co < 8; co++) bv[co] = bias[cbase + wv * 8 + co];
    #pragma unroll
    for (int dy = 0; dy < 2; dy++)
        #pragma unroll
        for (int dx = 0; dx < 2; dx++) {
            ushort8 pk;
            #pragma unroll
            for (int co = 0; co < 8; co++)
                pk[co] = f2bf(acc[dy][dx][co] + bv[co]);   // no relu on init
            int h = h0 + ty * 2 + dy, w = w0 + tx * 2 + dx;
            *(ushort8*)(outp + (((size_t)n * HW + h * 112 + w) << 7) + cbase + wv * 8) = pk;
        }
}

// ---------------- MFMA implicit-GEMM 3x3 conv, 128->128, bf16 NHWC ----------------
// Block: 256 thr (4 waves), tile M=128 px (8 rows x 16 cols), N=128 couts.
// Wave: 64px x 64co (acc[4][4]). 36 K-steps (s = q*9 + tap), 18 phases of 2.
// W: quad-buffered s_w[4][4096]; batch(P+1) issued at phase start; BARRIER A
// with COUNTED vmcnt(4) (P+1 stays in flight); BARRIER B lgkm-only.
#define AS 40           // s_in elems per px (32 + 8 pad) -> 80B stride

template<bool STORE>
__global__ __launch_bounds__(256, 3) void conv_mfma(
    const u16* __restrict__ in,     // [16][12544][128] bf16
    const u16* __restrict__ wbs,    // [36][4096] bf16 per-step LDS images
    const float* __restrict__ bias, // [128]
    u16* __restrict__ outp,         // [16][12544][128] bf16 (unused if !STORE)
    float* __restrict__ partial)    // [16][98][128] f32 per-block pooled sums
{
    __shared__ u16 s_in[180 * AS];          // 14,400 B
    __shared__ u16 s_w[4][4096];            // 32,768 B quad-buffer
    float* s_pool = (float*)s_in;           // overlay (after K-loop)

    const int tile = blockIdx.x;            // 0..97
    const int n    = blockIdx.y;
    const int h0 = (tile / 7) * 8, w0 = (tile % 7) * 16;
    const int tid = threadIdx.x, lane = tid & 63;
    const int wid = tid >> 6, wm = wid >> 1, wn = wid & 1;
    const int l15 = lane & 15, l4 = lane >> 4;

    const u16* in_n = in + ((size_t)n * HW << 7);

    // W staging: wave wid covers elems [wid*1024, wid*1024+1024) of each step
    // image via 2 gload16 (lane-linear dest, coalesced source).
    const u16* wsrc_base = wbs + wid * 1024 + (lane << 3);
    u16* wdst_base = &s_w[0][0] + wid * 1024;

    // ---- prologue: issue W(0), W(1) ----
    #pragma unroll
    for (int s01 = 0; s01 < 2; ++s01) {
        const u16* src = wsrc_base + (s01 << 12);
        u16* dst = wdst_base + (s01 << 12);
        gload16(src, dst);
        gload16(src + 512, dst + 512);
    }

    // ---- stage A(q=0): 180 px x 32 cin (halo, zero-padded) ----
    #pragma unroll
    for (int r2 = 0; r2 < 3; ++r2) {
        int g = tid + (r2 << 8);
        if (g < 720) {
            int px = g >> 2, c8 = (g & 3) << 3;
            int hh = px / 18, ww2 = px - hh * 18;
            int gh = h0 + hh - 1, gw = w0 + ww2 - 1;
            uint4 v = make_uint4(0, 0, 0, 0);
            if ((unsigned)gh < 112u && (unsigned)gw < 112u)
                v = *(const uint4*)(in_n + ((size_t)(gh * 112 + gw) << 7) + c8);
            *(uint4*)(s_in + px * AS + c8) = v;
        }
    }

    f32x4 acc[4][4];
    #pragma unroll
    for (int i = 0; i < 4; ++i)
        #pragma unroll
        for (int j = 0; j < 4; ++j)
            #pragma unroll
            for (int e = 0; e < 4; ++e) acc[i][j][e] = 0.f;

    int a_base[4], b_base[4];
    #pragma unroll
    for (int fi = 0; fi < 4; ++fi) a_base[fi] = (wm * 4 + fi) * 18 + l15;
    #pragma unroll
    for (int nj = 0; nj < 4; ++nj)
        b_base[nj] = (wn * 64 + nj * 16 + l15) * 32 + ((l4 ^ ((l15 >> 1) & 3)) << 3);

    __syncthreads();    // drains all: A(0) + W bufs 0,1 in LDS

    #pragma unroll
    for (int P = 0; P < 18; ++P) {
        const int s0 = 2 * P, s1 = 2 * P + 1;

        // issue batch(P+1) = W(s0+2), W(s1+2) into bufs (s0+2)&3, (s1+2)&3
        #pragma unroll
        for (int d2 = 2; d2 < 4; ++d2) {
            const int sp = s0 + d2;
            if (sp < 36) {
                const u16* src = wsrc_base + (sp << 12);
                u16* dst = wdst_base + ((sp & 3) << 12);
                gload16(src, dst);
                gload16(src + 512, dst + 512);
            }
        }

        // ---- BARRIER A: batch(P) landed everywhere; batch(P+1) stays in
        // flight across the barrier (counted, T4). Last phase has no newer
        // batch, so drain there.
        if (P < 17) asm volatile("s_waitcnt vmcnt(4)" ::: "memory");
        else        asm volatile("s_waitcnt vmcnt(0)" ::: "memory");
        __builtin_amdgcn_s_barrier();
        __builtin_amdgcn_sched_barrier(0);

        if (s0 % 9 != 8) {
            // ===== fused pipelined phase (both steps in same q) =====
            const int t0 = s0 % 9, kh0 = t0 / 3, kw0 = t0 - kh0 * 3;
            const int t1 = s1 % 9, kh1 = t1 / 3, kw1 = t1 - kh1 * 3;
            bf16x8 a0[4], b0[4], a1[4], b1[4];
            #pragma unroll
            for (int fi = 0; fi < 4; ++fi) {
                const u16* p = s_in + (a_base[fi] + kh0 * 18 + kw0) * AS + (l4 << 3);
                a0[fi] = __builtin_bit_cast(bf16x8, *(const short8*)p);
            }
            const u16* rb0 = &s_w[s0 & 3][0];
            #pragma unroll
            for (int nj = 0; nj < 4; ++nj)
                b0[nj] = __builtin_bit_cast(bf16x8, *(const short8*)(rb0 + b_base[nj]));
            #pragma unroll
            for (int fi = 0; fi < 4; ++fi) {
                const u16* p = s_in + (a_base[fi] + kh1 * 18 + kw1) * AS + (l4 << 3);
                a1[fi] = __builtin_bit_cast(bf16x8, *(const short8*)p);
            }
            __builtin_amdgcn_s_setprio(1);
            #pragma unroll
            for (int fi = 0; fi < 4; ++fi)
                #pragma unroll
                for (int nj = 0; nj < 4; ++nj)
                    acc[fi][nj] = __builtin_amdgcn_mfma_f32_16x16x32_bf16(
                        a0[fi], b0[nj], acc[fi][nj], 0, 0, 0);
            __builtin_amdgcn_s_setprio(0);
            const u16* rb1 = &s_w[s1 & 3][0];
            #pragma unroll
            for (int nj = 0; nj < 4; ++nj)
                b1[nj] = __builtin_bit_cast(bf16x8, *(const short8*)(rb1 + b_base[nj]));
            __builtin_amdgcn_s_setprio(1);
            #pragma unroll
            for (int fi = 0; fi < 4; ++fi)
                #pragma unroll
                for (int nj = 0; nj < 4; ++nj)
                    acc[fi][nj] = __builtin_amdgcn_mfma_f32_16x16x32_bf16(
                        a1[fi], b1[nj], acc[fi][nj], 0, 0, 0);
            __builtin_amdgcn_s_setprio(0);
        } else {
            // ===== q-boundary phase: step s0, restage s_in, step s1 =====
            {
                const int t = s0 % 9, kh = t / 3, kw = t - kh * 3;
                bf16x8 a[4], b[4];
                #pragma unroll
                for (int fi = 0; fi < 4; ++fi) {
                    const u16* p = s_in + (a_base[fi] + kh * 18 + kw) * AS + (l4 << 3);
                    a[fi] = __builtin_bit_cast(bf16x8, *(const short8*)p);
                }
                const u16* rb = &s_w[s0 & 3][0];
                #pragma unroll
                for (int nj = 0; nj < 4; ++nj)
                    b[nj] = __builtin_bit_cast(bf16x8, *(const short8*)(rb + b_base[nj]));
                __builtin_amdgcn_s_setprio(1);
                #pragma unroll
                for (int fi = 0; fi < 4; ++fi)
                    #pragma unroll
                    for (int nj = 0; nj < 4; ++nj)
                        acc[fi][nj] = __builtin_amdgcn_mfma_f32_16x16x32_bf16(
                            a[fi], b[nj], acc[fi][nj], 0, 0, 0);
                __builtin_amdgcn_s_setprio(0);
            }
            {
                const int qn = s0 / 9 + 1;
                asm volatile("s_waitcnt lgkmcnt(0)" ::: "memory");
                __builtin_amdgcn_s_barrier();       // all waves done reading q
                #pragma unroll
                for (int r2 = 0; r2 < 3; ++r2) {
                    int g = tid + (r2 << 8);
                    if (g < 720) {
                        int px = g >> 2, c8 = (g & 3) << 3;
                        int hh = px / 18, ww2 = px - hh * 18;
                        int gh = h0 + hh - 1, gw = w0 + ww2 - 1;
                        uint4 v = make_uint4(0, 0, 0, 0);
                        if ((unsigned)gh < 112u && (unsigned)gw < 112u)
                            v = *(const uint4*)(in_n + ((size_t)(gh * 112 + gw) << 7)
                                                + (qn << 5) + c8);
                        *(uint4*)(s_in + px * AS + c8) = v;
                    }
                }
                asm volatile("s_waitcnt lgkmcnt(0)" ::: "memory");
                __builtin_amdgcn_s_barrier();       // new A visible
                __builtin_amdgcn_sched_barrier(0);
            }
            {
                const int t = s1 % 9, kh = t / 3, kw = t - kh * 3;
                bf16x8 a[4], b[4];
                #pragma unroll
                for (int fi = 0; fi < 4; ++fi) {
                    const u16* p = s_in + (a_base[fi] + kh * 18 + kw) * AS + (l4 << 3);
                    a[fi] = __builtin_bit_cast(bf16x8, *(const short8*)p);
                }
                const u16* rb = &s_w[s1 & 3][0];
                #pragma unroll
                for (int nj = 0; nj < 4; ++nj)
                    b[nj] = __builtin_bit_cast(bf16x8, *(const short8*)(rb + b_base[nj]));
                __builtin_amdgcn_s_setprio(1);
                #pragma unroll
                for (int fi = 0; fi < 4; ++fi)
                    #pragma unroll
                    for (int nj = 0; nj < 4; ++nj)
                        acc[fi][nj] = __builtin_amdgcn_mfma_f32_16x16x32_bf16(
                            a[fi], b[nj], acc[fi][nj], 0, 0, 0);
                __builtin_amdgcn_s_setprio(0);
            }
        }

        // ---- BARRIER B: all reads of bufs 2P,2P+1 done before phase P+1
        // overwrites (2P+2)&3. LDS-count only -- NO vmem drain (T4).
        asm volatile("s_waitcnt lgkmcnt(0)" ::: "memory");
        __builtin_amdgcn_s_barrier();
        __builtin_amdgcn_sched_barrier(0);

        // -------- phase-boundary q-restage (after s1 ends q) --------
        if (s1 % 9 == 8 && s1 != 35) {
            const int qn = s1 / 9 + 1;
            #pragma unroll
            for (int r2 = 0; r2 < 3; ++r2) {
                int g = tid + (r2 << 8);
                if (g < 720) {
                    int px = g >> 2, c8 = (g & 3) << 3;
                    int hh = px / 18, ww2 = px - hh * 18;
                    int gh = h0 + hh - 1, gw = w0 + ww2 - 1;
                    uint4 v = make_uint4(0, 0, 0, 0);
                    if ((unsigned)gh < 112u && (unsigned)gw < 112u)
                        v = *(const uint4*)(in_n + ((size_t)(gh * 112 + gw) << 7)
                                            + (qn << 5) + c8);
                    *(uint4*)(s_in + px * AS + c8) = v;
                }
            }
            asm volatile("s_waitcnt lgkmcnt(0)" ::: "memory");
            __builtin_amdgcn_s_barrier();
            __builtin_amdgcn_sched_barrier(0);
        }
    }

    // ---- epilogue: bias + relu, optional bf16 NHWC stores, fused pooling ----
    // D layout: col = lane&15 (cout), row = l4*4 + j (pixel-within-16)
    float bv[4], ps[4];
    #pragma unroll
    for (int nj = 0; nj < 4; ++nj) { bv[nj] = bias[wn * 64 + nj * 16 + l15]; ps[nj] = 0.f; }
    u16* out_n = outp + ((size_t)n * HW << 7);
    #pragma unroll
    for (int fi = 0; fi < 4; ++fi) {
        int h = h0 + wm * 4 + fi;
        #pragma unroll
        for (int j = 0; j < 4; ++j) {
            int w = w0 + (l4 << 2) + j;
            u16* pr = out_n + ((size_t)(h * 112 + w) << 7);
            #pragma unroll
            for (int nj = 0; nj < 4; ++nj) {
                float v = fmaxf(acc[fi][nj][j] + bv[nj], 0.f);
                ps[nj] += v;
                if (STORE) pr[wn * 64 + nj * 16 + l15] = f2bf(v);
            }
        }
    }
    #pragma unroll
    for (int nj = 0; nj < 4; ++nj) {
        ps[nj] += __shfl_xor(ps[nj], 16, 64);
        ps[nj] += __shfl_xor(ps[nj], 32, 64);
    }
    __syncthreads();    // all s_in reads long done; reuse as pool buffer
    if (l4 == 0) {
        #pragma unroll
        for (int nj = 0; nj < 4; ++nj)
            s_pool[wm * 128 + wn * 64 + nj * 16 + l15] = ps[nj];
    }
    __syncthreads();
    if (tid < 128)
        partial[((size_t)n * NTILE + tile) * 128 + tid] = s_pool[tid] + s_pool[128 + tid];
}

// ---------------- per-(depth,sample): reduce partials + 100 dot-128 ----------------
__global__ __launch_bounds__(128) void logits_k(
    const float* __restrict__ partial,  // [4][16][98][128]
    const float* __restrict__ cw,       // [4][100][128]
    const float* __restrict__ cb,       // [4][100]
    float* __restrict__ lg)             // [4][16][100]
{
    const int i = blockIdx.x, n = blockIdx.y;
    const int tid = threadIdx.x;
    __shared__ float pool[128];
    const float* pp = partial + ((size_t)(i * NB + n) * NTILE) * 128;
    float s = 0.f;
    for (int t = 0; t < NTILE; ++t) s += pp[t * 128 + tid];
    pool[tid] = s * (1.f / HW);
    __syncthreads();
    if (tid < NCLS) {
        const float* wp = cw + ((size_t)i * NCLS + tid) * CCH;
        float a = cb[i * NCLS + tid];
        #pragma unroll
        for (int c = 0; c < CCH; c += 4) {
            float4 w4 = *(const float4*)(wp + c);
            a += pool[c] * w4.x + pool[c + 1] * w4.y
               + pool[c + 2] * w4.z + pool[c + 3] * w4.w;
        }
        lg[(i * NB + n) * NCLS + tid] = a;
    }
}

// ---------------- early-exit selection ----------------
__global__ __launch_bounds__(256) void select_k(
    const float* __restrict__ lg,   // [4][16][100]
    float* __restrict__ out)        // [16][100]
{
    __shared__ float slg[4 * NB * NCLS];
    __shared__ int chosen[NB];
    const int tid = threadIdx.x;
    for (int e = tid; e < 4 * NB * NCLS; e += 256) slg[e] = lg[e];
    __syncthreads();
    if (tid < NB) {
        int n = tid, ch = 3;
        for (int i = 0; i < 3; i++) {
            const float* row = &slg[(i * NB + n) * NCLS];
            float m = -1e30f;
            for (int j = 0; j < NCLS; j++) m = fmaxf(m, row[j]);
            float se = 0.f;
            for (int j = 0; j < NCLS; j++) se += expf(row[j] - m);
            if (1.f / se >= 0.9f) { ch = i; break; }
        }
        chosen[n] = ch;
    }
    __syncthreads();
    for (int e = tid; e < NB * NCLS; e += 256) {
        int n = e / NCLS, j = e % NCLS;
        out[e] = slg[(chosen[n] * NB + n) * NCLS + j];
    }
}

extern "C" void kernel_launch(void* const* d_in, const int* in_sizes, int n_in,
                              void* d_out, int out_size, void* d_ws, size_t ws_size,
                              hipStream_t stream) {
    const float* x       = (const float*)d_in[0];
    const float* init_w  = (const float*)d_in[1];
    const float* init_b  = (const float*)d_in[2];
    const float* block_w = (const float*)d_in[3];
    const float* block_b = (const float*)d_in[4];
    const float* cls_w   = (const float*)d_in[5];
    const float* cls_b   = (const float*)d_in[6];
    float* out = (float*)d_out;

    char* ws = (char*)d_ws;
    u16* fA        = (u16*)ws;                      // 51,380,224 B
    u16* fB        = (u16*)(ws + 51380224);         // 51,380,224 B
    u16* wbs       = (u16*)(ws + 102760448);        //  1,179,648 B
    float* partial = (float*)(ws + 103940096);      // 4*16*98*128*4 = 3,211,264 B
    float* lgbuf   = (float*)(ws + 107151360);      // 4*16*100*4 = 25,600 B

    convert_w<<<2304, 256, 0, stream>>>(block_w, wbs);
    conv_init<<<dim3(49, 4, NB), 256, 0, stream>>>(
        x, init_w + 2 * 128 * 27, init_b + 2 * 128, fA);

    u16* cur = fA;
    u16* nxt = fB;
    for (int i = 0; i < 4; ++i) {
        if (i < 3)
            conv_mfma<true><<<dim3(NTILE, NB), 256, 0, stream>>>(
                cur, wbs + (size_t)i * 147456, block_b + (i * 3 + 2) * 128, nxt,
                partial + (size_t)i * NB * NTILE * 128);
        else
            conv_mfma<false><<<dim3(NTILE, NB), 256, 0, stream>>>(
                cur, wbs + (size_t)i * 147456, block_b + (i * 3 + 2) * 128, nxt,
                partial + (size_t)i * NB * NTILE * 128);
        u16* t = cur; cur = nxt; nxt = t;
    }

    logits_k<<<dim3(4, NB), 128, 0, stream>>>(partial, cls_w, cls_b, lgbuf);
    select_k<<<1, 256, 0, stream>>>(lgbuf, out);
}

// Round 16
// 297.914 us; speedup vs baseline: 1.0847x; 1.0847x over previous
//
#include <hip/hip_runtime.h>
#include <hip/hip_bf16.h>

// MSDNet on MI355X. Only scale 2's chain matters (scales 0/1 dead), and
// final_logits == logits at depth 3.
// conv_mfma v12 = v8/r12 (70.4us/conv, best) with TRIPLE-buffered W
// (24KB) -> LDS 38.9KB -> 4 blocks/CU (16 waves): block-level drift lets
// one block's MFMA phase overlap another's LDS-read phase (r12 counters
// showed the two pipes serializing at 3 blocks). Single-step phases,
// ONE barrier/step, counted vmcnt(2) (W(s+2) in flight across barriers).

typedef unsigned int uint;
typedef unsigned short u16;
typedef __bf16 bf16x8 __attribute__((ext_vector_type(8)));
typedef short short8 __attribute__((ext_vector_type(8)));
typedef unsigned short ushort8 __attribute__((ext_vector_type(8)));
typedef float f32x4 __attribute__((ext_vector_type(4)));

#define NB   16
#define CCH  128
#define NCLS 100
#define HW   12544      // 112*112
#define NTILE 98        // 14 h-tiles x 7 w-tiles per image

__device__ __forceinline__ u16 f2bf(float f) {
    uint u = __float_as_uint(f);
    return (u16)((u + 0x7fffu + ((u >> 16) & 1u)) >> 16);
}

__device__ __forceinline__ void gload16(const u16* g, u16* l) {
    __builtin_amdgcn_global_load_lds(
        (const __attribute__((address_space(1))) uint*)g,
        (__attribute__((address_space(3))) uint*)l, 16, 0, 0);
}

// ---------------- weight convert: block_w[d][2][co][ci][kh][kw] f32 ->
// per-step LDS images wbs[d][s][4096]: slot (co,gpos,e) holds
// W[tap(s)][co][ q(s)*32 + (gpos ^ ((co>>1)&3))*8 + e ]   (s = q*9 + tap)
__global__ __launch_bounds__(256) void convert_w(
    const float* __restrict__ bw, u16* __restrict__ wbs)
{
    int idx = blockIdx.x * 256 + threadIdx.x;        // 4 * 36 * 4096
    if (idx >= 4 * 147456) return;
    int d = idx / 147456, r = idx % 147456;
    int s = r >> 12;                 // 0..35
    int p = r & 4095;
    int co = p >> 5, gpos = (p >> 3) & 3, e = p & 7;
    int q = s / 9, t = s % 9;
    int cin = q * 32 + ((gpos ^ ((co >> 1) & 3)) << 3) + e;
    float v = bw[(((size_t)(d * 3 + 2) * 128 + co) * 128 + cin) * 9 + t];
    wbs[idx] = f2bf(v);
}

// ---------------- init conv: cin=3, fp32 VALU, NCHW fp32 in -> NHWC bf16 out ----------------
__global__ __launch_bounds__(256) void conv_init(
    const float* __restrict__ in,    // [16][3][112][112]
    const float* __restrict__ wgt,   // [128][3][3][3]
    const float* __restrict__ bias,  // [128]
    u16* __restrict__ outp)          // [16][12544][128] bf16
{
    const int tile = blockIdx.x;          // 0..48 (16x16 tiles)
    const int cg   = blockIdx.y;          // 0..3  (32 couts)
    const int n    = blockIdx.z;
    const int h0 = (tile / 7) * 16, w0 = (tile % 7) * 16;
    const int tid = threadIdx.x;
    const int sid = tid & 63, wv = tid >> 6;
    const int tx = sid & 7, ty = sid >> 3;

    __shared__ float s_in[3][18][18];
    __shared__ float s_w[3][9][32];

    float acc[2][2][8];
    #pragma unroll
    for (int a = 0; a < 2; a++)
        #pragma unroll
        for (int b = 0; b < 2; b++)
            #pragma unroll
            for (int c = 0; c < 8; c++) acc[a][b][c] = 0.f;

    const float* in_n = in + (size_t)n * 3 * HW;
    const int cbase = cg * 32;

    for (int e = tid; e < 3 * 324; e += 256) {
        int ck = e / 324, p = e % 324;
        int y = p / 18, x = p % 18;
        int gh = h0 + y - 1, gw = w0 + x - 1;
        float v = 0.f;
        if ((unsigned)gh < 112u && (unsigned)gw < 112u)
            v = in_n[(size_t)ck * HW + gh * 112 + gw];
        s_in[ck][y][x] = v;
    }
    for (int e = tid; e < 3 * 9 * 32; e += 256) {
        int co = e / 27, r = e % 27;
        int ck = r / 9, kidx = r % 9;
        s_w[ck][kidx][co] = wgt[((size_t)(cbase + co) * 3 + ck) * 9 + kidx];
    }
    __syncthreads();

    #pragma unroll
    for (int ck = 0; ck < 3; ck++) {
        float rowv[4][4];
        #pragma unroll
        for (int r = 0; r < 4; r++) {
            float2 a  = *(const float2*)&s_in[ck][ty * 2 + r][tx * 2];
            float2 b2 = *(const float2*)&s_in[ck][ty * 2 + r][tx * 2 + 2];
            rowv[r][0] = a.x; rowv[r][1] = a.y;
            rowv[r][2] = b2.x; rowv[r][3] = b2.y;
        }
        #pragma unroll
        for (int kh = 0; kh < 3; kh++)
            #pragma unroll
            for (int kw = 0; kw < 3; kw++) {
                float i00 = rowv[kh][kw],     i01 = rowv[kh][kw + 1];
                float i10 = rowv[kh + 1][kw], i11 = rowv[kh + 1][kw + 1];
                const float* wp = &s_w[ck][kh * 3 + kw][wv * 8];
                #pragma unroll
                for (int co = 0; co < 8; co++) {
                    float wval = wp[co];
                    acc[0][0][co] += i00 * wval;
                    acc[0][1][co] += i01 * wval;
                    acc[1][0][co] += i10 * wval;
                    acc[1][1][co] += i11 * wval;
                }
            }
    }

    float bv[8];
    #pragma unroll
    for (int co = 0; co < 8; co++) bv[co] = bias[cbase + wv * 8 + co];
    #pragma unroll
    for (int dy = 0; dy < 2; dy++)
        #pragma unroll
        for (int dx = 0; dx < 2; dx++) {
            ushort8 pk;
            #pragma unroll
            for (int co = 0; co < 8; co++)
                pk[co] = f2bf(acc[dy][dx][co] + bv[co]);   // no relu on init
            int h = h0 + ty * 2 + dy, w = w0 + tx * 2 + dx;
            *(ushort8*)(outp + (((size_t)n * HW + h * 112 + w) << 7) + cbase + wv * 8) = pk;
        }
}

// ---------------- MFMA implicit-GEMM 3x3 conv, 128->128, bf16 NHWC ----------------
// Block: 256 thr (4 waves), tile M=128 px (8 rows x 16 cols), N=128 couts.
// Wave: 64px x 64co (acc[4][4]). 36 K-steps (s = q*9 + tap), single-step
// phases: issue W(s+2) -> read frags (buf s%3) -> MFMA -> vmcnt(2) (W(s+2)
// stays in flight) -> lgkm + barrier. W triple-buffered s_w[3][4096];
// A q-streamed s_in[180][40]. LDS 38.9KB -> 4 blocks/CU.
#define AS 40           // s_in elems per px (32 + 8 pad) -> 80B stride

template<bool STORE>
__global__ __launch_bounds__(256, 4) void conv_mfma(
    const u16* __restrict__ in,     // [16][12544][128] bf16
    const u16* __restrict__ wbs,    // [36][4096] bf16 per-step LDS images
    const float* __restrict__ bias, // [128]
    u16* __restrict__ outp,         // [16][12544][128] bf16 (unused if !STORE)
    float* __restrict__ partial)    // [16][98][128] f32 per-block pooled sums
{
    __shared__ u16 s_in[180 * AS];          // 14,400 B
    __shared__ u16 s_w[3][4096];            // 24,576 B triple-buffer
    float* s_pool = (float*)s_in;           // overlay (after K-loop)

    const int tile = blockIdx.x;            // 0..97
    const int n    = blockIdx.y;
    const int h0 = (tile / 7) * 8, w0 = (tile % 7) * 16;
    const int tid = threadIdx.x, lane = tid & 63;
    const int wid = tid >> 6, wm = wid >> 1, wn = wid & 1;
    const int l15 = lane & 15, l4 = lane >> 4;

    const u16* in_n = in + ((size_t)n * HW << 7);

    // W staging: wave wid covers elems [wid*1024, wid*1024+1024) of each step
    // image via 2 gload16 (lane-linear dest, coalesced source).
    const u16* wsrc_base = wbs + wid * 1024 + (lane << 3);
    u16* wdst_base = &s_w[0][0] + wid * 1024;

    // ---- prologue: issue W(0)->buf0, W(1)->buf1 ----
    #pragma unroll
    for (int s01 = 0; s01 < 2; ++s01) {
        const u16* src = wsrc_base + (s01 << 12);
        u16* dst = wdst_base + (s01 << 12);
        gload16(src, dst);
        gload16(src + 512, dst + 512);
    }

    // ---- stage A(q=0): 180 px x 32 cin (halo, zero-padded) ----
    #pragma unroll
    for (int r2 = 0; r2 < 3; ++r2) {
        int g = tid + (r2 << 8);
        if (g < 720) {
            int px = g >> 2, c8 = (g & 3) << 3;
            int hh = px / 18, ww2 = px - hh * 18;
            int gh = h0 + hh - 1, gw = w0 + ww2 - 1;
            uint4 v = make_uint4(0, 0, 0, 0);
            if ((unsigned)gh < 112u && (unsigned)gw < 112u)
                v = *(const uint4*)(in_n + ((size_t)(gh * 112 + gw) << 7) + c8);
            *(uint4*)(s_in + px * AS + c8) = v;
        }
    }

    f32x4 acc[4][4];
    #pragma unroll
    for (int i = 0; i < 4; ++i)
        #pragma unroll
        for (int j = 0; j < 4; ++j)
            #pragma unroll
            for (int e = 0; e < 4; ++e) acc[i][j][e] = 0.f;

    int a_base[4], b_base[4];
    #pragma unroll
    for (int fi = 0; fi < 4; ++fi) a_base[fi] = (wm * 4 + fi) * 18 + l15;
    #pragma unroll
    for (int nj = 0; nj < 4; ++nj)
        b_base[nj] = (wn * 64 + nj * 16 + l15) * 32 + ((l4 ^ ((l15 >> 1) & 3)) << 3);

    __syncthreads();    // full drain: A(0) + W bufs 0,1 in LDS

    #pragma unroll
    for (int s = 0; s < 36; ++s) {
        // issue W(s+2) into buf (s+2)%3 (its reads finished at end of s-1)
        if (s + 2 < 36) {
            const u16* src = wsrc_base + ((s + 2) << 12);
            u16* dst = wdst_base + (((s + 2) % 3) << 12);
            gload16(src, dst);
            gload16(src + 512, dst + 512);
        }

        const int t = s % 9, kh = t / 3, kw = t - kh * 3;
        bf16x8 a[4], b[4];
        #pragma unroll
        for (int fi = 0; fi < 4; ++fi) {
            const u16* p = s_in + (a_base[fi] + kh * 18 + kw) * AS + (l4 << 3);
            a[fi] = __builtin_bit_cast(bf16x8, *(const short8*)p);
        }
        const u16* rb = &s_w[s % 3][0];
        #pragma unroll
        for (int nj = 0; nj < 4; ++nj)
            b[nj] = __builtin_bit_cast(bf16x8, *(const short8*)(rb + b_base[nj]));

        #pragma unroll
        for (int fi = 0; fi < 4; ++fi)
            #pragma unroll
            for (int nj = 0; nj < 4; ++nj)
                acc[fi][nj] = __builtin_amdgcn_mfma_f32_16x16x32_bf16(
                    a[fi], b[nj], acc[fi][nj], 0, 0, 0);

        // ---- end-of-step sync: counted vmcnt (W(s+2) stays in flight);
        // everyone's W(s+1) landed + all reads of buf s%3 done.
        if (s < 35) {
            if (s + 2 < 36) asm volatile("s_waitcnt vmcnt(2)" ::: "memory");
            else            asm volatile("s_waitcnt vmcnt(0)" ::: "memory");
            asm volatile("s_waitcnt lgkmcnt(0)" ::: "memory");
            __builtin_amdgcn_s_barrier();
            __builtin_amdgcn_sched_barrier(0);
        }

        // ---- q-boundary: restage s_in with next cin-chunk ----
        if (t == 8 && s < 35) {
            const int qn = s / 9 + 1;
            #pragma unroll
            for (int r2 = 0; r2 < 3; ++r2) {
                int g = tid + (r2 << 8);
                if (g < 720) {
                    int px = g >> 2, c8 = (g & 3) << 3;
                    int hh = px / 18, ww2 = px - hh * 18;
                    int gh = h0 + hh - 1, gw = w0 + ww2 - 1;
                    uint4 v = make_uint4(0, 0, 0, 0);
                    if ((unsigned)gh < 112u && (unsigned)gw < 112u)
                        v = *(const uint4*)(in_n + ((size_t)(gh * 112 + gw) << 7)
                                            + (qn << 5) + c8);
                    *(uint4*)(s_in + px * AS + c8) = v;
                }
            }
            asm volatile("s_waitcnt lgkmcnt(0)" ::: "memory");
            __builtin_amdgcn_s_barrier();       // new A visible
            __builtin_amdgcn_sched_barrier(0);
        }
    }

    // ---- epilogue: bias + relu, optional bf16 NHWC stores, fused pooling ----
    // D layout: col = lane&15 (cout), row = l4*4 + j (pixel-within-16)
    float bv[4], ps[4];
    #pragma unroll
    for (int nj = 0; nj < 4; ++nj) { bv[nj] = bias[wn * 64 + nj * 16 + l15]; ps[nj] = 0.f; }
    u16* out_n = outp + ((size_t)n * HW << 7);
    #pragma unroll
    for (int fi = 0; fi < 4; ++fi) {
        int h = h0 + wm * 4 + fi;
        #pragma unroll
        for (int j = 0; j < 4; ++j) {
            int w = w0 + (l4 << 2) + j;
            u16* pr = out_n + ((size_t)(h * 112 + w) << 7);
            #pragma unroll
            for (int nj = 0; nj < 4; ++nj) {
                float v = fmaxf(acc[fi][nj][j] + bv[nj], 0.f);
                ps[nj] += v;
                if (STORE) pr[wn * 64 + nj * 16 + l15] = f2bf(v);
            }
        }
    }
    #pragma unroll
    for (int nj = 0; nj < 4; ++nj) {
        ps[nj] += __shfl_xor(ps[nj], 16, 64);
        ps[nj] += __shfl_xor(ps[nj], 32, 64);
    }
    __syncthreads();    // all s_in reads long done; reuse as pool buffer
    if (l4 == 0) {
        #pragma unroll
        for (int nj = 0; nj < 4; ++nj)
            s_pool[wm * 128 + wn * 64 + nj * 16 + l15] = ps[nj];
    }
    __syncthreads();
    if (tid < 128)
        partial[((size_t)n * NTILE + tile) * 128 + tid] = s_pool[tid] + s_pool[128 + tid];
}

// ---------------- per-(depth,sample): reduce partials + 100 dot-128 ----------------
__global__ __launch_bounds__(128) void logits_k(
    const float* __restrict__ partial,  // [4][16][98][128]
    const float* __restrict__ cw,       // [4][100][128]
    const float* __restrict__ cb,       // [4][100]
    float* __restrict__ lg)             // [4][16][100]
{
    const int i = blockIdx.x, n = blockIdx.y;
    const int tid = threadIdx.x;
    __shared__ float pool[128];
    const float* pp = partial + ((size_t)(i * NB + n) * NTILE) * 128;
    float s = 0.f;
    for (int t = 0; t < NTILE; ++t) s += pp[t * 128 + tid];
    pool[tid] = s * (1.f / HW);
    __syncthreads();
    if (tid < NCLS) {
        const float* wp = cw + ((size_t)i * NCLS + tid) * CCH;
        float a = cb[i * NCLS + tid];
        #pragma unroll
        for (int c = 0; c < CCH; c += 4) {
            float4 w4 = *(const float4*)(wp + c);
            a += pool[c] * w4.x + pool[c + 1] * w4.y
               + pool[c + 2] * w4.z + pool[c + 3] * w4.w;
        }
        lg[(i * NB + n) * NCLS + tid] = a;
    }
}

// ---------------- early-exit selection ----------------
__global__ __launch_bounds__(256) void select_k(
    const float* __restrict__ lg,   // [4][16][100]
    float* __restrict__ out)        // [16][100]
{
    __shared__ float slg[4 * NB * NCLS];
    __shared__ int chosen[NB];
    const int tid = threadIdx.x;
    for (int e = tid; e < 4 * NB * NCLS; e += 256) slg[e] = lg[e];
    __syncthreads();
    if (tid < NB) {
        int n = tid, ch = 3;
        for (int i = 0; i < 3; i++) {
            const float* row = &slg[(i * NB + n) * NCLS];
            float m = -1e30f;
            for (int j = 0; j < NCLS; j++) m = fmaxf(m, row[j]);
            float se = 0.f;
            for (int j = 0; j < NCLS; j++) se += expf(row[j] - m);
            if (1.f / se >= 0.9f) { ch = i; break; }
        }
        chosen[n] = ch;
    }
    __syncthreads();
    for (int e = tid; e < NB * NCLS; e += 256) {
        int n = e / NCLS, j = e % NCLS;
        out[e] = slg[(chosen[n] * NB + n) * NCLS + j];
    }
}

extern "C" void kernel_launch(void* const* d_in, const int* in_sizes, int n_in,
                              void* d_out, int out_size, void* d_ws, size_t ws_size,
                              hipStream_t stream) {
    const float* x       = (const float*)d_in[0];
    const float* init_w  = (const float*)d_in[1];
    const float* init_b  = (const float*)d_in[2];
    const float* block_w = (const float*)d_in[3];
    const float* block_b = (const float*)d_in[4];
    const float* cls_w   = (const float*)d_in[5];
    const float* cls_b   = (const float*)d_in[6];
    float* out = (float*)d_out;

    char* ws = (char*)d_ws;
    u16* fA        = (u16*)ws;                      // 51,380,224 B
    u16* fB        = (u16*)(ws + 51380224);         // 51,380,224 B
    u16* wbs       = (u16*)(ws + 102760448);        //  1,179,648 B
    float* partial = (float*)(ws + 103940096);      // 4*16*98*128*4 = 3,211,264 B
    float* lgbuf   = (float*)(ws + 107151360);      // 4*16*100*4 = 25,600 B

    convert_w<<<2304, 256, 0, stream>>>(block_w, wbs);
    conv_init<<<dim3(49, 4, NB), 256, 0, stream>>>(
        x, init_w + 2 * 128 * 27, init_b + 2 * 128, fA);

    u16* cur = fA;
    u16* nxt = fB;
    for (int i = 0; i < 4; ++i) {
        if (i < 3)
            conv_mfma<true><<<dim3(NTILE, NB), 256, 0, stream>>>(
                cur, wbs + (size_t)i * 147456, block_b + (i * 3 + 2) * 128, nxt,
                partial + (size_t)i * NB * NTILE * 128);
        else
            conv_mfma<false><<<dim3(NTILE, NB), 256, 0, stream>>>(
                cur, wbs + (size_t)i * 147456, block_b + (i * 3 + 2) * 128, nxt,
                partial + (size_t)i * NB * NTILE * 128);
        u16* t = cur; cur = nxt; nxt = t;
    }

    logits_k<<<dim3(4, NB), 128, 0, stream>>>(partial, cls_w, cls_b, lgbuf);
    select_k<<<1, 256, 0, stream>>>(lgbuf, out);
}